// Round 17
// baseline (1327.588 us; speedup 1.0000x reference)
//
#include <hip/hip_runtime.h>
#include <math.h>

#define CC   256
#define DD   16
#define HH   128
#define WWD  128
#define CRD  32
#define DSTN 16
#define DIN  64
#define LN   1024
#define NSEQ 16
#define GCH  16
#define CLEN 64
#define LOG2E 1.44269504088896f
#define LN2   0.69314718055995f

// measurement-probe reps (idempotent; balanced so all 4 kernels surface in top-5)
#define REPK1 16
#define REPK2 24
#define REPK3 32
#define REPK45 4

typedef float f32x4 __attribute__((ext_vector_type(4)));

// ---------------- workspace layout (floats) ----------------
constexpr size_t NTOK = (size_t)NSEQ * LN;                          // 16384 tokens
constexpr size_t OFF_TOKN = 0;                                      // [16][1024][32]
constexpr size_t OFF_YM   = OFF_TOKN + NTOK*CRD;                    // [16][1024][32]
constexpr size_t OFF_P    = OFF_YM   + NTOK*CRD;                    // [2][16][16][64][16]
constexpr size_t OFF_HE   = OFF_P    + 2*NTOK*DIN;
constexpr size_t OFF_XS   = OFF_HE   + 2*NTOK*DIN;                  // [2][16][1024][64]
constexpr size_t OFF_ZS   = OFF_XS   + 2*NTOK*DIN;                  // [2][16][1024][64]
constexpr size_t OFF_REC  = OFF_ZS   + 2*NTOK*DIN;                  // [2][16][1024][36]
constexpr size_t OFF_INWT = OFF_REC  + 2*NTOK*36;                   // [2][32][128]
constexpr size_t OFF_XPT  = OFF_INWT + 2*(size_t)CRD*128;           // [2][64][34]
constexpr size_t OFF_OW2  = OFF_XPT  + 2*(size_t)DIN*34;            // [2][64][32]
constexpr size_t OFF_AN   = OFF_OW2  + 2*(size_t)DIN*CRD;           // [2][64][16]

// fast native transcendentals via amdgcn builtins
__device__ __forceinline__ float fexp(float x) {
  return __builtin_amdgcn_exp2f(x * LOG2E);
}
__device__ __forceinline__ float siluf(float x) {
  return x * __builtin_amdgcn_rcpf(1.0f + fexp(-x));
}
__device__ __forceinline__ float softplusf(float z) {
  return (z > 20.f) ? z : __builtin_amdgcn_logf(1.0f + fexp(z)) * LN2;
}

// ---------------- K1: tokenize (256->32 proj + LN) + prep tables ----------------
__global__ __launch_bounds__(256) void bm3d_k1_token_ln(
    const float* __restrict__ x, const float* __restrict__ w_in,
    const float* __restrict__ ln_w, const float* __restrict__ ln_b,
    const float* __restrict__ inw_f, const float* __restrict__ inw_b,
    const float* __restrict__ xp_f,  const float* __restrict__ xp_b,
    const float* __restrict__ ow_f,  const float* __restrict__ ow_b,
    const float* __restrict__ al_f,  const float* __restrict__ al_b,
    float* __restrict__ tokn,
    float* __restrict__ inwT, float* __restrict__ xpT,
    float* __restrict__ ow2, float* __restrict__ An) {
  __shared__ float xv[CC*CRD];      // [c][ws] 32KB
  __shared__ float wT[CC*33];       // [c][r] padded 33KB
  __shared__ float zt[CRD][33];     // [r][ws]
  __shared__ float mu_s[32], rs_s[32];
  int b = blockIdx.x & 511;         // rep = blockIdx.x >> 9 (identical work)
  int d = b >> 5, hs = b & 31;
  int t = threadIdx.x;

  // prep tables (blocks 0..31 of each rep; identical values -> deterministic)
  if (b < 32) {
    int gt = b*256 + t;
    for (int i = gt; i < 2*CRD*128; i += 8192) {      // inwT[dir][dd][e]
      int dir = i >> 12, rem = i & 4095, dd = rem >> 7, e = rem & 127;
      inwT[i] = (dir ? inw_b : inw_f)[e*CRD + dd];
    }
    for (int i = gt; i < 2*DIN*34; i += 8192) {       // xpT[dir][dd][e]
      int dir = i / (DIN*34), rem = i - dir*(DIN*34);
      int dd = rem / 34, e = rem - dd*34;
      xpT[i] = (dir ? xp_b : xp_f)[e*DIN + dd];
    }
    for (int i = gt; i < 2*DIN*CRD; i += 8192) {      // ow2[dir][dd][r]
      int dir = i >> 11, rem = i & 2047, dd = rem >> 5, r = rem & 31;
      ow2[i] = (dir ? ow_b : ow_f)[r*DIN + dd];
    }
    for (int i = gt; i < 2*DIN*DSTN; i += 8192) {     // An = -exp(A_log)*log2e
      int dir = i >> 10, rem = i & 1023;
      An[i] = -expf((dir ? al_b : al_f)[rem]) * LOG2E;
    }
  }

  // in-LDS transpose of w_in: wT[c][r] = w_in[r][c]
  for (int it = 0; it < 8; ++it) {
    int f4 = t + it*256;            // 2048 float4
    float4 v = ((const float4*)w_in)[f4];
    int f = f4*4;
    int r = f >> 8, c = f & 255;
    wT[(c+0)*33 + r] = v.x; wT[(c+1)*33 + r] = v.y;
    wT[(c+2)*33 + r] = v.z; wT[(c+3)*33 + r] = v.w;
  }
  // load x[c, d, 4hs, 4ws]
  {
    int wsx = t & 31, cg = t >> 5;
    const float4* xbase = (const float4*)(x + ((size_t)d*HH + 4*hs)*WWD) + wsx;
    #pragma unroll 8
    for (int i = 0; i < 32; ++i) {
      int c = cg*32 + i;
      xv[c*CRD + wsx] = xbase[(size_t)c*(DD*HH*WWD/4)].x;
    }
  }
  __syncthreads();
  // z[r][ws] = sum_c wT[c][r] * xv[c][ws]
  {
    int r = t & 31, wq = t >> 5;
    float a0=0.f,a1=0.f,a2=0.f,a3=0.f;
    #pragma unroll 8
    for (int c = 0; c < CC; ++c) {
      float w = wT[c*33 + r];
      float4 xq = *(const float4*)(xv + c*CRD + wq*4);
      a0 = fmaf(w, xq.x, a0); a1 = fmaf(w, xq.y, a1);
      a2 = fmaf(w, xq.z, a2); a3 = fmaf(w, xq.w, a3);
    }
    zt[r][wq*4+0] = a0; zt[r][wq*4+1] = a1;
    zt[r][wq*4+2] = a2; zt[r][wq*4+3] = a3;
  }
  __syncthreads();
  if (t < 32) {
    float mu = 0.f;
    for (int r = 0; r < 32; ++r) mu += zt[r][t];
    mu *= (1.0f/32.0f);
    float var = 0.f;
    for (int r = 0; r < 32; ++r) { float dl = zt[r][t]-mu; var = fmaf(dl, dl, var); }
    var *= (1.0f/32.0f);
    mu_s[t] = mu; rs_s[t] = 1.0f/sqrtf(var + 1e-5f);
  }
  __syncthreads();
  float* outp = tokn + ((size_t)d*LN + hs*32)*CRD;
  for (int it = t; it < 1024; it += 256) {
    int w2 = it >> 5, r2 = it & 31;
    outp[it] = (zt[r2][w2]-mu_s[w2])*rs_s[w2]*ln_w[r2] + ln_b[r2];
  }
}

// ---------------- K2: prescan (weights-in-registers) + chunk P/h_end ----------------
__global__ __launch_bounds__(256, 2) void bm3d_k2_prescan(
    const float* __restrict__ tokn, const float* __restrict__ ws_inwT,
    const float* __restrict__ ws_xpT,
    const float* __restrict__ cw_f, const float* __restrict__ cb_f,
    const float* __restrict__ dtw_f, const float* __restrict__ dtb_f,
    const float* __restrict__ cw_b, const float* __restrict__ cb_b,
    const float* __restrict__ dtw_b, const float* __restrict__ dtb_b,
    const float* __restrict__ An,
    float* __restrict__ xs_g, float* __restrict__ zs_g, float* __restrict__ rec_g,
    float* __restrict__ P_ws, float* __restrict__ hend_ws) {
  __shared__ float tk[67*CRD];      // 8.6KB
  __shared__ float xr[67*DIN];      // 17.2KB
  __shared__ float xs[64*DIN];      // 16KB
  __shared__ float dbk[64*20];      // 5KB
  int b = blockIdx.x & 511;         // rep = blockIdx.x >> 9
  int dir = b >> 8, n = (b >> 4) & 15, g = b & 15;
  int l0 = g*CLEN;
  int t = threadIdx.x;
  size_t segbase = ((size_t)dir*NSEQ + n)*LN + l0;

  for (int i = t; i < 67*CRD; i += 256) {
    int row = i >> 5, col = i & 31;
    int lb = l0 - 3 + row;
    float v = 0.f;
    if (lb >= 0) {
      int lo = dir ? (LN-1-lb) : lb;
      v = tokn[((size_t)n*LN + lo)*CRD + col];
    }
    tk[i] = v;
  }
  __syncthreads();
  {
    int ep = t & 63, rq = t >> 6;
    const float* wp = ws_inwT + (size_t)dir*CRD*128 + 2*ep;
    float w0[CRD], w1[CRD];
    #pragma unroll
    for (int dd = 0; dd < CRD; ++dd) {
      float2 wv = *(const float2*)(wp + dd*128);
      w0[dd] = wv.x; w1[dd] = wv.y;
    }
    int r0 = rq*17, r1 = (rq == 3) ? 67 : (r0 + 17);
    for (int r = r0; r < r1; ++r) {
      const float* tkr = tk + r*CRD;
      float a0 = 0.f, a1 = 0.f;
      #pragma unroll
      for (int dq = 0; dq < 8; ++dq) {
        float4 tv = *(const float4*)(tkr + dq*4);
        a0 = fmaf(tv.x, w0[dq*4+0], a0); a1 = fmaf(tv.x, w1[dq*4+0], a1);
        a0 = fmaf(tv.y, w0[dq*4+1], a0); a1 = fmaf(tv.y, w1[dq*4+1], a1);
        a0 = fmaf(tv.z, w0[dq*4+2], a0); a1 = fmaf(tv.z, w1[dq*4+2], a1);
        a0 = fmaf(tv.w, w0[dq*4+3], a0); a1 = fmaf(tv.w, w1[dq*4+3], a1);
      }
      if (ep < 32) {
        xr[r*DIN + 2*ep]   = a0;
        xr[r*DIN + 2*ep+1] = a1;
      } else if (r >= 3) {
        int row = r - 3, e = 2*ep - 64;
        float2 zv = make_float2(siluf(a0), siluf(a1));
        *(float2*)(zs_g + (segbase + row)*DIN + e) = zv;
      }
    }
  }
  __syncthreads();
  {
    const float* cw = dir ? cw_b : cw_f;
    const float* cb = dir ? cb_b : cb_f;
    for (int i = t; i < 64*DIN; i += 256) {
      int r = i >> 6, dd = i & 63;
      float acc = cb[dd];
      #pragma unroll
      for (int k = 0; k < 4; ++k) acc = fmaf(cw[dd*4+k], xr[(r+k)*DIN + dd], acc);
      float v = siluf(acc);
      xs[i] = v;
      xs_g[segbase*DIN + i] = v;
    }
  }
  __syncthreads();
  {
    int e = t & 63, rq = t >> 6;
    if (e < 34) {
      const float* xwp = ws_xpT + (size_t)dir*DIN*34 + e;
      float xw[DIN];
      #pragma unroll
      for (int dd = 0; dd < DIN; ++dd) xw[dd] = xwp[dd*34];
      int slot = (e < 2) ? e : (e + 2);
      for (int r = rq*16; r < rq*16 + 16; ++r) {
        const float* xsr = xs + r*DIN;
        float acc = 0.f;
        #pragma unroll
        for (int dq = 0; dq < 16; ++dq) {
          float4 xvv = *(const float4*)(xsr + dq*4);
          acc = fmaf(xvv.x, xw[dq*4+0], acc);
          acc = fmaf(xvv.y, xw[dq*4+1], acc);
          acc = fmaf(xvv.z, xw[dq*4+2], acc);
          acc = fmaf(xvv.w, xw[dq*4+3], acc);
        }
        if (e < 18) dbk[r*20 + slot] = acc;
        rec_g[(segbase + r)*36 + slot] = acc;
      }
    }
  }
  __syncthreads();
  {
    int dd = t >> 2, sq = t & 3;
    const float* Ap = An + ((size_t)dir*DIN + dd)*DSTN + sq*4;
    float A0 = Ap[0], A1 = Ap[1], A2 = Ap[2], A3 = Ap[3];
    const float* dtw = dir ? dtw_b : dtw_f;
    const float* dtb = dir ? dtb_b : dtb_f;
    float dw0 = dtw[dd*2+0], dw1 = dtw[dd*2+1], dbb = dtb[dd];
    float h0=0.f,h1=0.f,h2=0.f,h3=0.f, P0=1.f,P1=1.f,P2=1.f,P3=1.f;
    #pragma unroll 4
    for (int i = 0; i < CLEN; ++i) {
      float2 dt01 = *(const float2*)(dbk + i*20);
      float dtv = softplusf(fmaf(dt01.x, dw0, fmaf(dt01.y, dw1, dbb)));
      float xv  = xs[i*DIN + dd];
      float4 Bv = *(const float4*)(dbk + i*20 + 4 + sq*4);
      float dtx = dtv*xv;
      float a0 = __builtin_amdgcn_exp2f(dtv*A0), a1 = __builtin_amdgcn_exp2f(dtv*A1);
      float a2 = __builtin_amdgcn_exp2f(dtv*A2), a3 = __builtin_amdgcn_exp2f(dtv*A3);
      P0 *= a0; P1 *= a1; P2 *= a2; P3 *= a3;
      h0 = fmaf(a0, h0, dtx*Bv.x); h1 = fmaf(a1, h1, dtx*Bv.y);
      h2 = fmaf(a2, h2, dtx*Bv.z); h3 = fmaf(a3, h3, dtx*Bv.w);
    }
    size_t pbase = ((((size_t)dir*NSEQ + n)*GCH + g)*DIN + dd)*DSTN + sq*4;
    *(float4*)(P_ws + pbase)    = make_float4(P0,P1,P2,P3);
    *(float4*)(hend_ws + pbase) = make_float4(h0,h1,h2,h3);
  }
}

// ---------------- K3: LDS-staged both-dir scan + gate + combine + 64->32 proj ----------------
__global__ __launch_bounds__(512, 4) void bm3d_k3_scan(
    const float* __restrict__ xs_g, const float* __restrict__ zs_g,
    const float* __restrict__ rec_g, const float* __restrict__ ws_ow2,
    const float* __restrict__ dtw_f, const float* __restrict__ dtb_f,
    const float* __restrict__ dtw_b, const float* __restrict__ dtb_b,
    const float* __restrict__ An,
    const float* __restrict__ P_ws, const float* __restrict__ hend_ws,
    const float* __restrict__ D_f, const float* __restrict__ D_b,
    float* __restrict__ ym) {
  __shared__ float ys[2*64*65];     // 33.3KB (padded)
  __shared__ float ow[2*DIN*CRD];   // 16KB
  __shared__ float st_rec[2*16*36];
  __shared__ float st_xs[2*16*DIN];
  __shared__ float st_zs[2*16*DIN];
  int b = blockIdx.x & 255;         // rep = blockIdx.x >> 8
  int n = b >> 4, g = b & 15;
  int t = threadIdx.x;
  for (int i = t; i < 2*DIN*CRD; i += 512) ow[i] = ws_ow2[i];

  int dir = t >> 8, dd = (t >> 2) & 63, sq = t & 3;
  int gd = dir ? (15 - g) : g;
  const float* Ap = An + ((size_t)dir*DIN + dd)*DSTN + sq*4;
  float A0 = Ap[0], A1 = Ap[1], A2 = Ap[2], A3 = Ap[3];
  const float* dtw = dir ? dtw_b : dtw_f;
  const float* dtb = dir ? dtb_b : dtb_f;
  float dw0 = dtw[dd*2+0], dw1 = dtw[dd*2+1], dbb = dtb[dd];
  float Dp = (dir ? D_b : D_f)[dd];
  float h0=0.f,h1=0.f,h2=0.f,h3=0.f;
  for (int gp = 0; gp < gd; ++gp) {
    size_t pb = ((((size_t)dir*NSEQ + n)*GCH + gp)*DIN + dd)*DSTN + sq*4;
    float4 Pv = *(const float4*)(P_ws + pb);
    float4 Hv = *(const float4*)(hend_ws + pb);
    h0 = fmaf(Pv.x, h0, Hv.x); h1 = fmaf(Pv.y, h1, Hv.y);
    h2 = fmaf(Pv.z, h2, Hv.z); h3 = fmaf(Pv.w, h3, Hv.w);
  }
  float* ysd = ys + dir*4160;
  const float* recd = st_rec + dir*576;
  const float* xsd  = st_xs + dir*1024;
  const float* zsd  = st_zs + dir*1024;

  for (int tile = 0; tile < 4; ++tile) {
    __syncthreads();
    if (t < 288) {
      int sdir = (t >= 144), rem = t - sdir*144;
      int tok = rem / 9, q = rem - tok*9;
      int sgd = sdir ? (15-g) : g;
      size_t gtok = ((size_t)sdir*NSEQ + n)*LN + sgd*CLEN + tile*16 + tok;
      *(float4*)(st_rec + sdir*576 + tok*36 + q*4) =
          *(const float4*)(rec_g + gtok*36 + q*4);
    }
    {
      int sdir = t >> 8, rem = t & 255;
      int tok = rem >> 4, q = rem & 15;
      int sgd = sdir ? (15-g) : g;
      size_t gtok = ((size_t)sdir*NSEQ + n)*LN + sgd*CLEN + tile*16 + tok;
      *(float4*)(st_xs + sdir*1024 + tok*64 + q*4) =
          *(const float4*)(xs_g + gtok*64 + q*4);
      *(float4*)(st_zs + sdir*1024 + tok*64 + q*4) =
          *(const float4*)(zs_g + gtok*64 + q*4);
    }
    __syncthreads();
    #pragma unroll 4
    for (int i = 0; i < 16; ++i) {
      float2 dt01 = *(const float2*)(recd + i*36);
      float4 Bv = *(const float4*)(recd + i*36 + 4 + sq*4);
      float4 Cv = *(const float4*)(recd + i*36 + 20 + sq*4);
      float xv = xsd[i*DIN + dd];
      float zv = zsd[i*DIN + dd];
      float dtv = softplusf(fmaf(dt01.x, dw0, fmaf(dt01.y, dw1, dbb)));
      float dtx = dtv*xv;
      float a0 = __builtin_amdgcn_exp2f(dtv*A0), a1 = __builtin_amdgcn_exp2f(dtv*A1);
      float a2 = __builtin_amdgcn_exp2f(dtv*A2), a3 = __builtin_amdgcn_exp2f(dtv*A3);
      h0 = fmaf(a0, h0, dtx*Bv.x); h1 = fmaf(a1, h1, dtx*Bv.y);
      h2 = fmaf(a2, h2, dtx*Bv.z); h3 = fmaf(a3, h3, dtx*Bv.w);
      float p = h0*Cv.x + h1*Cv.y + h2*Cv.z + h3*Cv.w;
      p += __shfl_xor(p, 1);
      p += __shfl_xor(p, 2);
      if (sq == 0) {
        int ig = tile*16 + i;
        int li = dir ? (63 - ig) : ig;
        ysd[li*65 + dd] = (p + Dp*xv)*zv;
      }
    }
  }
  __syncthreads();
  {
    int q = t >> 3, rb = (t & 7) * 4;
    const float* ys0 = ys + q*65;
    const float* ys1 = ys + 4160 + q*65;
    const float* wf = ow;
    const float* wb = ow + 2048;
    float a0=0.f,a1=0.f,a2=0.f,a3=0.f;
    #pragma unroll 8
    for (int dd2 = 0; dd2 < DIN; ++dd2) {
      float yf = ys0[dd2], yb = ys1[dd2];
      const float* wfr = wf + dd2*CRD + rb;
      const float* wbr = wb + dd2*CRD + rb;
      a0 = fmaf(yf, wfr[0], fmaf(yb, wbr[0], a0));
      a1 = fmaf(yf, wfr[1], fmaf(yb, wbr[1], a1));
      a2 = fmaf(yf, wfr[2], fmaf(yb, wbr[2], a2));
      a3 = fmaf(yf, wfr[3], fmaf(yb, wbr[3], a3));
    }
    float4 v = make_float4(0.5f*a0, 0.5f*a1, 0.5f*a2, 0.5f*a3);
    *(float4*)(ym + ((size_t)n*LN + g*CLEN + q)*CRD + rb) = v;
  }
}

// ---------------- K45: 32->256 projection + 4x4 upsample ----------------
__global__ __launch_bounds__(256) void bm3d_k45_out(
    const float* __restrict__ ym, const float* __restrict__ w_out,
    float* __restrict__ out) {
  __shared__ float wo[CC*CRD];      // 32KB
  __shared__ float ymt[32*33];      // padded
  int b = blockIdx.x & 511;         // rep = blockIdx.x >> 9
  int d = b >> 5, hs = b & 31;
  int t = threadIdx.x;
  for (int i = t; i < CC*CRD; i += 256) wo[i] = w_out[i];
  const float* fb = ym + ((size_t)d*LN + hs*32)*CRD;
  for (int i = t; i < 1024; i += 256) {
    int wq = i >> 5, r = i & 31;
    ymt[wq*33 + r] = fb[i];
  }
  __syncthreads();
  int q = t & 31, cg = t >> 5;
  const float* fr = ymt + q*33;
  for (int ci = 0; ci < 32; ++ci) {
    int c = cg*32 + ci;
    const float* wr = wo + c*CRD;
    float acc = 0.f;
    #pragma unroll 8
    for (int r = 0; r < 32; ++r) acc = fmaf(wr[r], fr[r], acc);
    f32x4 v = { acc, acc, acc, acc };
    size_t rowbase = (((size_t)c*DD + d)*HH + 4*hs)*WWD + 4*q;
    __builtin_nontemporal_store(v, (f32x4*)(out + rowbase));
    __builtin_nontemporal_store(v, (f32x4*)(out + rowbase +   WWD));
    __builtin_nontemporal_store(v, (f32x4*)(out + rowbase + 2*WWD));
    __builtin_nontemporal_store(v, (f32x4*)(out + rowbase + 3*WWD));
  }
}

extern "C" void kernel_launch(void* const* d_in, const int* in_sizes, int n_in,
                              void* d_out, int out_size, void* d_ws, size_t ws_size,
                              hipStream_t stream) {
  const float* x      = (const float*)d_in[0];
  const float* w_in   = (const float*)d_in[1];
  const float* w_out  = (const float*)d_in[2];
  const float* ln_w   = (const float*)d_in[3];
  const float* ln_b   = (const float*)d_in[4];
  const float* mf_in_w   = (const float*)d_in[5];
  const float* mf_conv_w = (const float*)d_in[6];
  const float* mf_conv_b = (const float*)d_in[7];
  const float* mf_xproj  = (const float*)d_in[8];
  const float* mf_dt_w   = (const float*)d_in[9];
  const float* mf_dt_b   = (const float*)d_in[10];
  const float* mf_A_log  = (const float*)d_in[11];
  const float* mf_D      = (const float*)d_in[12];
  const float* mf_out_w  = (const float*)d_in[13];
  const float* mb_in_w   = (const float*)d_in[14];
  const float* mb_conv_w = (const float*)d_in[15];
  const float* mb_conv_b = (const float*)d_in[16];
  const float* mb_xproj  = (const float*)d_in[17];
  const float* mb_dt_w   = (const float*)d_in[18];
  const float* mb_dt_b   = (const float*)d_in[19];
  const float* mb_A_log  = (const float*)d_in[20];
  const float* mb_D      = (const float*)d_in[21];
  const float* mb_out_w  = (const float*)d_in[22];

  float* ws   = (float*)d_ws;
  float* tokn = ws + OFF_TOKN;
  float* ym   = ws + OFF_YM;
  float* Pw   = ws + OFF_P;
  float* He   = ws + OFF_HE;
  float* xs_g = ws + OFF_XS;
  float* zs_g = ws + OFF_ZS;
  float* recg = ws + OFF_REC;
  float* inwT = ws + OFF_INWT;
  float* xpT  = ws + OFF_XPT;
  float* ow2  = ws + OFF_OW2;
  float* An   = ws + OFF_AN;

  // MEASUREMENT PROBE on the R15 champion: balanced reps so all 4 kernels
  // surface in the top-5 with counters. dur/rep ~= per-kernel cost.
  bm3d_k1_token_ln<<<512*REPK1, 256, 0, stream>>>(x, w_in, ln_w, ln_b,
                                            mf_in_w, mb_in_w, mf_xproj, mb_xproj,
                                            mf_out_w, mb_out_w, mf_A_log, mb_A_log,
                                            tokn, inwT, xpT, ow2, An);
  bm3d_k2_prescan<<<512*REPK2, 256, 0, stream>>>(tokn, inwT, xpT,
                                           mf_conv_w, mf_conv_b, mf_dt_w, mf_dt_b,
                                           mb_conv_w, mb_conv_b, mb_dt_w, mb_dt_b,
                                           An, xs_g, zs_g, recg, Pw, He);
  bm3d_k3_scan<<<256*REPK3, 512, 0, stream>>>(xs_g, zs_g, recg, ow2,
                                        mf_dt_w, mf_dt_b, mb_dt_w, mb_dt_b,
                                        An, Pw, He, mf_D, mb_D, ym);
  bm3d_k45_out<<<512*REPK45, 256, 0, stream>>>(ym, w_out, (float*)d_out);
}

// Round 18
// 124.749 us; speedup vs baseline: 10.6421x; 10.6421x over previous
//
#include <hip/hip_runtime.h>
#include <math.h>

#define CC   256
#define DD   16
#define HH   128
#define WWD  128
#define CRD  32
#define DSTN 16
#define DIN  64
#define LN   1024
#define NSEQ 16
#define GCH  16
#define CLEN 64
#define LOG2E 1.44269504088896f
#define LN2   0.69314718055995f

typedef float f32x4 __attribute__((ext_vector_type(4)));

// ---------------- workspace layout (floats) ----------------
constexpr size_t NTOK = (size_t)NSEQ * LN;                          // 16384 tokens
constexpr size_t OFF_TOKN = 0;                                      // [16][1024][32]
constexpr size_t OFF_YM   = OFF_TOKN + NTOK*CRD;                    // [16][1024][32]
constexpr size_t OFF_P    = OFF_YM   + NTOK*CRD;                    // [2][16][16][64][16]
constexpr size_t OFF_HE   = OFF_P    + 2*NTOK*DIN;
constexpr size_t OFF_PACK = OFF_HE   + 2*NTOK*DIN;                  // [2][16][1024][64][4]
constexpr size_t OFF_REC  = OFF_PACK + 2*NTOK*DIN*4;                // [2][16][1024][32] B|C
constexpr size_t OFF_INWT = OFF_REC  + 2*NTOK*32;                   // [2][32][128]
constexpr size_t OFF_XPT  = OFF_INWT + 2*(size_t)CRD*128;           // [2][64][34]
constexpr size_t OFF_OW2  = OFF_XPT  + 2*(size_t)DIN*34;            // [2][64][32]
constexpr size_t OFF_AN   = OFF_OW2  + 2*(size_t)DIN*CRD;           // [2][64][16]

// fast native transcendentals via amdgcn builtins
__device__ __forceinline__ float fexp(float x) {
  return __builtin_amdgcn_exp2f(x * LOG2E);
}
__device__ __forceinline__ float siluf(float x) {
  return x * __builtin_amdgcn_rcpf(1.0f + fexp(-x));
}
__device__ __forceinline__ float softplusf(float z) {
  return (z > 20.f) ? z : __builtin_amdgcn_logf(1.0f + fexp(z)) * LN2;
}

// ---------------- K1: tokenize (256->32 proj + LN) + prep tables ----------------
__global__ __launch_bounds__(256) void bm3d_k1_token_ln(
    const float* __restrict__ x, const float* __restrict__ w_in,
    const float* __restrict__ ln_w, const float* __restrict__ ln_b,
    const float* __restrict__ inw_f, const float* __restrict__ inw_b,
    const float* __restrict__ xp_f,  const float* __restrict__ xp_b,
    const float* __restrict__ ow_f,  const float* __restrict__ ow_b,
    const float* __restrict__ al_f,  const float* __restrict__ al_b,
    float* __restrict__ tokn,
    float* __restrict__ inwT, float* __restrict__ xpT,
    float* __restrict__ ow2, float* __restrict__ An) {
  __shared__ float xv[CC*CRD];      // [c][ws] 32KB
  __shared__ float wT[CC*33];       // [c][r] padded 33KB
  __shared__ float zt[CRD][33];     // [r][ws]
  __shared__ float mu_s[32], rs_s[32];
  int b = blockIdx.x;               // 512 = 16 d * 32 hs
  int d = b >> 5, hs = b & 31;
  int t = threadIdx.x;

  // prep tables (blocks 0..31 only; consumed by K2/K3)
  if (b < 32) {
    int gt = b*256 + t;
    for (int i = gt; i < 2*CRD*128; i += 8192) {      // inwT[dir][dd][e]
      int dir = i >> 12, rem = i & 4095, dd = rem >> 7, e = rem & 127;
      inwT[i] = (dir ? inw_b : inw_f)[e*CRD + dd];
    }
    for (int i = gt; i < 2*DIN*34; i += 8192) {       // xpT[dir][dd][e]
      int dir = i / (DIN*34), rem = i - dir*(DIN*34);
      int dd = rem / 34, e = rem - dd*34;
      xpT[i] = (dir ? xp_b : xp_f)[e*DIN + dd];
    }
    for (int i = gt; i < 2*DIN*CRD; i += 8192) {      // ow2[dir][dd][r]
      int dir = i >> 11, rem = i & 2047, dd = rem >> 5, r = rem & 31;
      ow2[i] = (dir ? ow_b : ow_f)[r*DIN + dd];
    }
    for (int i = gt; i < 2*DIN*DSTN; i += 8192) {     // An = -exp(A_log)*log2e
      int dir = i >> 10, rem = i & 1023;
      An[i] = -expf((dir ? al_b : al_f)[rem]) * LOG2E;
    }
  }

  // in-LDS transpose of w_in: wT[c][r] = w_in[r][c]
  for (int it = 0; it < 8; ++it) {
    int f4 = t + it*256;            // 2048 float4
    float4 v = ((const float4*)w_in)[f4];
    int f = f4*4;
    int r = f >> 8, c = f & 255;
    wT[(c+0)*33 + r] = v.x; wT[(c+1)*33 + r] = v.y;
    wT[(c+2)*33 + r] = v.z; wT[(c+3)*33 + r] = v.w;
  }
  // load x[c, d, 4hs, 4ws]
  {
    int wsx = t & 31, cg = t >> 5;
    const float4* xbase = (const float4*)(x + ((size_t)d*HH + 4*hs)*WWD) + wsx;
    #pragma unroll 8
    for (int i = 0; i < 32; ++i) {
      int c = cg*32 + i;
      xv[c*CRD + wsx] = xbase[(size_t)c*(DD*HH*WWD/4)].x;
    }
  }
  __syncthreads();
  // z[r][ws] = sum_c wT[c][r] * xv[c][ws]
  {
    int r = t & 31, wq = t >> 5;
    float a0=0.f,a1=0.f,a2=0.f,a3=0.f;
    #pragma unroll 8
    for (int c = 0; c < CC; ++c) {
      float w = wT[c*33 + r];
      float4 xq = *(const float4*)(xv + c*CRD + wq*4);
      a0 = fmaf(w, xq.x, a0); a1 = fmaf(w, xq.y, a1);
      a2 = fmaf(w, xq.z, a2); a3 = fmaf(w, xq.w, a3);
    }
    zt[r][wq*4+0] = a0; zt[r][wq*4+1] = a1;
    zt[r][wq*4+2] = a2; zt[r][wq*4+3] = a3;
  }
  __syncthreads();
  if (t < 32) {
    float mu = 0.f;
    for (int r = 0; r < 32; ++r) mu += zt[r][t];
    mu *= (1.0f/32.0f);
    float var = 0.f;
    for (int r = 0; r < 32; ++r) { float dl = zt[r][t]-mu; var = fmaf(dl, dl, var); }
    var *= (1.0f/32.0f);
    mu_s[t] = mu; rs_s[t] = 1.0f/sqrtf(var + 1e-5f);
  }
  __syncthreads();
  float* outp = tokn + ((size_t)d*LN + hs*32)*CRD;
  for (int it = t; it < 1024; it += 256) {
    int w2 = it >> 5, r2 = it & 31;
    outp[it] = (zt[r2][w2]-mu_s[w2])*rs_s[w2]*ln_w[r2] + ln_b[r2];
  }
}

// ---------------- K2: prescan + pack build + chunk P/h_end ----------------
// rec layout per token (32 floats): [0..15]=B, [16..31]=C
// pack layout per (token,dd) float4: {dtv, dtv*xv, zv, Dp*xv*zv}
__global__ __launch_bounds__(256, 2) void bm3d_k2_prescan(
    const float* __restrict__ tokn, const float* __restrict__ ws_inwT,
    const float* __restrict__ ws_xpT,
    const float* __restrict__ cw_f, const float* __restrict__ cb_f,
    const float* __restrict__ dtw_f, const float* __restrict__ dtb_f,
    const float* __restrict__ cw_b, const float* __restrict__ cb_b,
    const float* __restrict__ dtw_b, const float* __restrict__ dtb_b,
    const float* __restrict__ An,
    const float* __restrict__ D_f, const float* __restrict__ D_b,
    float* __restrict__ pack_g, float* __restrict__ rec_g,
    float* __restrict__ P_ws, float* __restrict__ hend_ws) {
  __shared__ float tk[67*CRD];      // 8.6KB
  __shared__ float xr[67*DIN];      // 17.2KB
  __shared__ float xs[64*DIN];      // 16KB
  __shared__ float zb[64*DIN];      // 16KB
  __shared__ float dbk[64*20];      // 5KB  [r][0..1]=dt01, [4..19]=B
  __shared__ float dts[64*DIN];     // 16KB  (total ~79KB -> 2 blocks/CU)
  int b = blockIdx.x;               // 512 = 2 dir * 16 n * 16 g
  int dir = b >> 8, n = (b >> 4) & 15, g = b & 15;
  int l0 = g*CLEN;
  int t = threadIdx.x;
  size_t segbase = ((size_t)dir*NSEQ + n)*LN + l0;

  for (int i = t; i < 67*CRD; i += 256) {
    int row = i >> 5, col = i & 31;
    int lb = l0 - 3 + row;
    float v = 0.f;
    if (lb >= 0) {
      int lo = dir ? (LN-1-lb) : lb;
      v = tokn[((size_t)n*LN + lo)*CRD + col];
    }
    tk[i] = v;
  }
  __syncthreads();
  // phase AB: in_proj (x -> xr; z -> silu -> zb)
  {
    int ep = t & 63, rq = t >> 6;
    const float* wp = ws_inwT + (size_t)dir*CRD*128 + 2*ep;
    float w0[CRD], w1[CRD];
    #pragma unroll
    for (int dd = 0; dd < CRD; ++dd) {
      float2 wv = *(const float2*)(wp + dd*128);
      w0[dd] = wv.x; w1[dd] = wv.y;
    }
    int r0 = rq*17, r1 = (rq == 3) ? 67 : (r0 + 17);
    for (int r = r0; r < r1; ++r) {
      const float* tkr = tk + r*CRD;
      float a0 = 0.f, a1 = 0.f;
      #pragma unroll
      for (int dq = 0; dq < 8; ++dq) {
        float4 tv = *(const float4*)(tkr + dq*4);
        a0 = fmaf(tv.x, w0[dq*4+0], a0); a1 = fmaf(tv.x, w1[dq*4+0], a1);
        a0 = fmaf(tv.y, w0[dq*4+1], a0); a1 = fmaf(tv.y, w1[dq*4+1], a1);
        a0 = fmaf(tv.z, w0[dq*4+2], a0); a1 = fmaf(tv.z, w1[dq*4+2], a1);
        a0 = fmaf(tv.w, w0[dq*4+3], a0); a1 = fmaf(tv.w, w1[dq*4+3], a1);
      }
      if (ep < 32) {
        xr[r*DIN + 2*ep]   = a0;
        xr[r*DIN + 2*ep+1] = a1;
      } else if (r >= 3) {
        int row = r - 3, e = 2*ep - 64;
        zb[row*DIN + e]   = siluf(a0);
        zb[row*DIN + e+1] = siluf(a1);
      }
    }
  }
  __syncthreads();
  // phase C: conv4 + silu -> xs
  {
    const float* cw = dir ? cw_b : cw_f;
    const float* cb = dir ? cb_b : cb_f;
    for (int i = t; i < 64*DIN; i += 256) {
      int r = i >> 6, dd = i & 63;
      float acc = cb[dd];
      #pragma unroll
      for (int k = 0; k < 4; ++k) acc = fmaf(cw[dd*4+k], xr[(r+k)*DIN + dd], acc);
      xs[i] = siluf(acc);
    }
  }
  __syncthreads();
  // phase D1: xproj (e<34): dt01+B -> dbk; B,C -> rec_g
  {
    int e = t & 63, rq = t >> 6;
    if (e < 34) {
      const float* xwp = ws_xpT + (size_t)dir*DIN*34 + e;
      float xw[DIN];
      #pragma unroll
      for (int dd = 0; dd < DIN; ++dd) xw[dd] = xwp[dd*34];
      int slot = (e < 2) ? e : (e + 2);
      for (int r = rq*16; r < rq*16 + 16; ++r) {
        const float* xsr = xs + r*DIN;
        float acc = 0.f;
        #pragma unroll
        for (int dq = 0; dq < 16; ++dq) {
          float4 xvv = *(const float4*)(xsr + dq*4);
          acc = fmaf(xvv.x, xw[dq*4+0], acc);
          acc = fmaf(xvv.y, xw[dq*4+1], acc);
          acc = fmaf(xvv.z, xw[dq*4+2], acc);
          acc = fmaf(xvv.w, xw[dq*4+3], acc);
        }
        if (e < 18) dbk[r*20 + slot] = acc;
        if (e >= 2) rec_g[(segbase + r)*32 + (e-2)] = acc;
      }
    }
  }
  __syncthreads();
  // phase D2: dtv once per (r,dd) -> dts LDS; pack -> global
  {
    int dd = t & 63, rq = t >> 6;
    const float* dtw = dir ? dtw_b : dtw_f;
    const float* dtb = dir ? dtb_b : dtb_f;
    float dw0 = dtw[dd*2+0], dw1 = dtw[dd*2+1], dbb = dtb[dd];
    float Dp = (dir ? D_b : D_f)[dd];
    for (int r = rq*16; r < rq*16 + 16; ++r) {
      float2 dt01 = *(const float2*)(dbk + r*20);
      float dtv = softplusf(fmaf(dt01.x, dw0, fmaf(dt01.y, dw1, dbb)));
      float xv = xs[r*DIN + dd], zv = zb[r*DIN + dd];
      dts[r*DIN + dd] = dtv;
      float4 pk = make_float4(dtv, dtv*xv, zv, Dp*xv*zv);
      *(float4*)(pack_g + ((segbase + r)*DIN + dd)*4) = pk;
    }
  }
  __syncthreads();
  // chunk-local scan: P, h_end (dts from LDS; no redundant softplus)
  {
    int dd = t >> 2, sq = t & 3;
    const float* Ap = An + ((size_t)dir*DIN + dd)*DSTN + sq*4;
    float A0 = Ap[0], A1 = Ap[1], A2 = Ap[2], A3 = Ap[3];
    float h0=0.f,h1=0.f,h2=0.f,h3=0.f, P0=1.f,P1=1.f,P2=1.f,P3=1.f;
    #pragma unroll 4
    for (int i = 0; i < CLEN; ++i) {
      float dtv = dts[i*DIN + dd];
      float dtx = dtv * xs[i*DIN + dd];
      float4 Bv = *(const float4*)(dbk + i*20 + 4 + sq*4);
      float a0 = __builtin_amdgcn_exp2f(dtv*A0), a1 = __builtin_amdgcn_exp2f(dtv*A1);
      float a2 = __builtin_amdgcn_exp2f(dtv*A2), a3 = __builtin_amdgcn_exp2f(dtv*A3);
      P0 *= a0; P1 *= a1; P2 *= a2; P3 *= a3;
      h0 = fmaf(a0, h0, dtx*Bv.x); h1 = fmaf(a1, h1, dtx*Bv.y);
      h2 = fmaf(a2, h2, dtx*Bv.z); h3 = fmaf(a3, h3, dtx*Bv.w);
    }
    size_t pbase = ((((size_t)dir*NSEQ + n)*GCH + g)*DIN + dd)*DSTN + sq*4;
    *(float4*)(P_ws + pbase)    = make_float4(P0,P1,P2,P3);
    *(float4*)(hend_ws + pbase) = make_float4(h0,h1,h2,h3);
  }
}

// ---------------- K3: LDS-staged both-dir scan (pack-driven) + combine + proj ----------------
__global__ __launch_bounds__(512, 2) void bm3d_k3_scan(
    const float* __restrict__ pack_g, const float* __restrict__ rec_g,
    const float* __restrict__ ws_ow2, const float* __restrict__ An,
    const float* __restrict__ P_ws, const float* __restrict__ hend_ws,
    float* __restrict__ ym) {
  __shared__ float ys[2*64*65];     // 33.3KB (padded)
  __shared__ float ow[2*DIN*CRD];   // 16KB
  __shared__ float st_rec[2*16*32]; // 4KB
  __shared__ float st_pk[2*16*DIN*4]; // 32KB  (total ~85KB)
  int b = blockIdx.x;               // 256 = 16 n * 16 g
  int n = b >> 4, g = b & 15;
  int t = threadIdx.x;
  for (int i = t; i < 2*DIN*CRD; i += 512) ow[i] = ws_ow2[i];

  int dir = t >> 8, dd = (t >> 2) & 63, sq = t & 3;
  int gd = dir ? (15 - g) : g;
  const float* Ap = An + ((size_t)dir*DIN + dd)*DSTN + sq*4;
  float A0 = Ap[0], A1 = Ap[1], A2 = Ap[2], A3 = Ap[3];
  float h0=0.f,h1=0.f,h2=0.f,h3=0.f;
  for (int gp = 0; gp < gd; ++gp) {
    size_t pb = ((((size_t)dir*NSEQ + n)*GCH + gp)*DIN + dd)*DSTN + sq*4;
    float4 Pv = *(const float4*)(P_ws + pb);
    float4 Hv = *(const float4*)(hend_ws + pb);
    h0 = fmaf(Pv.x, h0, Hv.x); h1 = fmaf(Pv.y, h1, Hv.y);
    h2 = fmaf(Pv.z, h2, Hv.z); h3 = fmaf(Pv.w, h3, Hv.w);
  }
  float* ysd = ys + dir*4160;
  const float* recd = st_rec + dir*512;
  const float* pkd  = st_pk + dir*4096;

  for (int tile = 0; tile < 4; ++tile) {
    __syncthreads();
    // stage pack: 2 dirs x 16 tok x 64 dd float4 = 2048 float4; 4 per thread
    #pragma unroll
    for (int k = 0; k < 4; ++k) {
      int i4 = t + k*512;             // 0..2047
      int sdir = i4 >> 10, rem = i4 & 1023;
      int sgd = sdir ? (15-g) : g;
      size_t gtok = ((size_t)sdir*NSEQ + n)*LN + sgd*CLEN + tile*16 + (rem >> 6);
      *(float4*)(st_pk + (sdir*1024 + rem)*4) =
          *(const float4*)(pack_g + (gtok*DIN + (rem & 63))*4);
    }
    // stage rec: 2 dirs x 16 tok x 8 float4 = 256 float4
    if (t < 256) {
      int sdir = t >> 7, rem = t & 127;
      int tok = rem >> 3, q = rem & 7;
      int sgd = sdir ? (15-g) : g;
      size_t gtok = ((size_t)sdir*NSEQ + n)*LN + sgd*CLEN + tile*16 + tok;
      *(float4*)(st_rec + sdir*512 + tok*32 + q*4) =
          *(const float4*)(rec_g + gtok*32 + q*4);
    }
    __syncthreads();
    #pragma unroll 4
    for (int i = 0; i < 16; ++i) {
      float4 pk = *(const float4*)(pkd + (i*DIN + dd)*4); // {dtv, dtx, zv, Dxz}
      float4 Bv = *(const float4*)(recd + i*32 + sq*4);
      float4 Cv = *(const float4*)(recd + i*32 + 16 + sq*4);
      float a0 = __builtin_amdgcn_exp2f(pk.x*A0), a1 = __builtin_amdgcn_exp2f(pk.x*A1);
      float a2 = __builtin_amdgcn_exp2f(pk.x*A2), a3 = __builtin_amdgcn_exp2f(pk.x*A3);
      h0 = fmaf(a0, h0, pk.y*Bv.x); h1 = fmaf(a1, h1, pk.y*Bv.y);
      h2 = fmaf(a2, h2, pk.y*Bv.z); h3 = fmaf(a3, h3, pk.y*Bv.w);
      float p = h0*Cv.x + h1*Cv.y + h2*Cv.z + h3*Cv.w;
      p += __shfl_xor(p, 1);
      p += __shfl_xor(p, 2);
      if (sq == 0) {
        int ig = tile*16 + i;
        int li = dir ? (63 - ig) : ig;
        ysd[li*65 + dd] = fmaf(p, pk.z, pk.w);   // (p + Dp*xv)*zv
      }
    }
  }
  __syncthreads();
  // combine + 64->32 projection: ym[token][r]
  {
    int q = t >> 3, rb = (t & 7) * 4;
    const float* ys0 = ys + q*65;
    const float* ys1 = ys + 4160 + q*65;
    const float* wf = ow;
    const float* wb = ow + 2048;
    float a0=0.f,a1=0.f,a2=0.f,a3=0.f;
    #pragma unroll 8
    for (int dd2 = 0; dd2 < DIN; ++dd2) {
      float yf = ys0[dd2], yb = ys1[dd2];
      const float* wfr = wf + dd2*CRD + rb;
      const float* wbr = wb + dd2*CRD + rb;
      a0 = fmaf(yf, wfr[0], fmaf(yb, wbr[0], a0));
      a1 = fmaf(yf, wfr[1], fmaf(yb, wbr[1], a1));
      a2 = fmaf(yf, wfr[2], fmaf(yb, wbr[2], a2));
      a3 = fmaf(yf, wfr[3], fmaf(yb, wbr[3], a3));
    }
    float4 v = make_float4(0.5f*a0, 0.5f*a1, 0.5f*a2, 0.5f*a3);
    *(float4*)(ym + ((size_t)n*LN + g*CLEN + q)*CRD + rb) = v;
  }
}

// ---------------- K45: 32->256 projection + 4x4 upsample ----------------
__global__ __launch_bounds__(256) void bm3d_k45_out(
    const float* __restrict__ ym, const float* __restrict__ w_out,
    float* __restrict__ out) {
  __shared__ float wo[CC*CRD];      // 32KB
  __shared__ float ymt[32*33];      // padded
  int b = blockIdx.x;               // 512 = 16 d * 32 hs
  int d = b >> 5, hs = b & 31;
  int t = threadIdx.x;
  for (int i = t; i < CC*CRD; i += 256) wo[i] = w_out[i];
  const float* fb = ym + ((size_t)d*LN + hs*32)*CRD;
  for (int i = t; i < 1024; i += 256) {
    int wq = i >> 5, r = i & 31;
    ymt[wq*33 + r] = fb[i];
  }
  __syncthreads();
  int q = t & 31, cg = t >> 5;
  const float* fr = ymt + q*33;
  for (int ci = 0; ci < 32; ++ci) {
    int c = cg*32 + ci;
    const float* wr = wo + c*CRD;
    float acc = 0.f;
    #pragma unroll 8
    for (int r = 0; r < 32; ++r) acc = fmaf(wr[r], fr[r], acc);
    f32x4 v = { acc, acc, acc, acc };
    size_t rowbase = (((size_t)c*DD + d)*HH + 4*hs)*WWD + 4*q;
    __builtin_nontemporal_store(v, (f32x4*)(out + rowbase));
    __builtin_nontemporal_store(v, (f32x4*)(out + rowbase +   WWD));
    __builtin_nontemporal_store(v, (f32x4*)(out + rowbase + 2*WWD));
    __builtin_nontemporal_store(v, (f32x4*)(out + rowbase + 3*WWD));
  }
}

extern "C" void kernel_launch(void* const* d_in, const int* in_sizes, int n_in,
                              void* d_out, int out_size, void* d_ws, size_t ws_size,
                              hipStream_t stream) {
  const float* x      = (const float*)d_in[0];
  const float* w_in   = (const float*)d_in[1];
  const float* w_out  = (const float*)d_in[2];
  const float* ln_w   = (const float*)d_in[3];
  const float* ln_b   = (const float*)d_in[4];
  const float* mf_in_w   = (const float*)d_in[5];
  const float* mf_conv_w = (const float*)d_in[6];
  const float* mf_conv_b = (const float*)d_in[7];
  const float* mf_xproj  = (const float*)d_in[8];
  const float* mf_dt_w   = (const float*)d_in[9];
  const float* mf_dt_b   = (const float*)d_in[10];
  const float* mf_A_log  = (const float*)d_in[11];
  const float* mf_D      = (const float*)d_in[12];
  const float* mf_out_w  = (const float*)d_in[13];
  const float* mb_in_w   = (const float*)d_in[14];
  const float* mb_conv_w = (const float*)d_in[15];
  const float* mb_conv_b = (const float*)d_in[16];
  const float* mb_xproj  = (const float*)d_in[17];
  const float* mb_dt_w   = (const float*)d_in[18];
  const float* mb_dt_b   = (const float*)d_in[19];
  const float* mb_A_log  = (const float*)d_in[20];
  const float* mb_D      = (const float*)d_in[21];
  const float* mb_out_w  = (const float*)d_in[22];

  float* ws   = (float*)d_ws;
  float* tokn = ws + OFF_TOKN;
  float* ym   = ws + OFF_YM;
  float* Pw   = ws + OFF_P;
  float* He   = ws + OFF_HE;
  float* pack = ws + OFF_PACK;
  float* recg = ws + OFF_REC;
  float* inwT = ws + OFF_INWT;
  float* xpT  = ws + OFF_XPT;
  float* ow2  = ws + OFF_OW2;
  float* An   = ws + OFF_AN;

  bm3d_k1_token_ln<<<512, 256, 0, stream>>>(x, w_in, ln_w, ln_b,
                                            mf_in_w, mb_in_w, mf_xproj, mb_xproj,
                                            mf_out_w, mb_out_w, mf_A_log, mb_A_log,
                                            tokn, inwT, xpT, ow2, An);
  bm3d_k2_prescan<<<512, 256, 0, stream>>>(tokn, inwT, xpT,
                                           mf_conv_w, mf_conv_b, mf_dt_w, mf_dt_b,
                                           mb_conv_w, mb_conv_b, mb_dt_w, mb_dt_b,
                                           An, mf_D, mb_D,
                                           pack, recg, Pw, He);
  bm3d_k3_scan<<<256, 512, 0, stream>>>(pack, recg, ow2, An, Pw, He, ym);
  bm3d_k45_out<<<512, 256, 0, stream>>>(ym, w_out, (float*)d_out);
}